// Round 8
// baseline (478.203 us; speedup 1.0000x reference)
//
#include <hip/hip_runtime.h>
#include <math.h>

#define NNODES 50000
#define NEDGES 100000
#define HALF_E 50000
#define HID 128
#define NKEYS (NEDGES + 2 * NNODES)  // edge keys, then node-half0, node-half1

// bucket decomposition: 256 keys per bucket
#define NB_E ((NEDGES + 255) >> 8)       // 391
#define NB_N2 ((2 * NNODES + 255) >> 8)  // 391
#define NB (NB_E + NB_N2)                // 782
#define PART_CHUNK 4096

// ===========================================================================
// bucket_count: LDS histogram of bucket sizes
// edge item key = col c; node item key = row r + (c >= HALF_E ? NNODES : 0)
// ===========================================================================
__global__ __launch_bounds__(256) void bucket_count_kernel(
    const int* __restrict__ rows, const int* __restrict__ cols,
    int* __restrict__ bucket_cnt, int nnz) {
  __shared__ int cnt[NB];
  for (int k = threadIdx.x; k < NB; k += 256) cnt[k] = 0;
  __syncthreads();
  int stride = gridDim.x * 256 * 4;
  for (int base = (blockIdx.x * 256 + threadIdx.x) * 4; base < nnz;
       base += stride) {
    if (base + 3 < nnz) {
      int4 r4 = *reinterpret_cast<const int4*>(rows + base);
      int4 c4 = *reinterpret_cast<const int4*>(cols + base);
      atomicAdd(&cnt[c4.x >> 8], 1);
      atomicAdd(&cnt[c4.y >> 8], 1);
      atomicAdd(&cnt[c4.z >> 8], 1);
      atomicAdd(&cnt[c4.w >> 8], 1);
      int k0 = r4.x + (c4.x >= HALF_E ? NNODES : 0);
      int k1 = r4.y + (c4.y >= HALF_E ? NNODES : 0);
      int k2 = r4.z + (c4.z >= HALF_E ? NNODES : 0);
      int k3 = r4.w + (c4.w >= HALF_E ? NNODES : 0);
      atomicAdd(&cnt[NB_E + (k0 >> 8)], 1);
      atomicAdd(&cnt[NB_E + (k1 >> 8)], 1);
      atomicAdd(&cnt[NB_E + (k2 >> 8)], 1);
      atomicAdd(&cnt[NB_E + (k3 >> 8)], 1);
    } else {
      for (int i = base; i < nnz; ++i) {
        int c = cols[i];
        int k = rows[i] + (c >= HALF_E ? NNODES : 0);
        atomicAdd(&cnt[c >> 8], 1);
        atomicAdd(&cnt[NB_E + (k >> 8)], 1);
      }
    }
  }
  __syncthreads();
  for (int k = threadIdx.x; k < NB; k += 256)
    if (cnt[k]) atomicAdd(&bucket_cnt[k], cnt[k]);
}

// exclusive scan of NB bucket counts, one block
__global__ __launch_bounds__(1024) void bucket_scan_kernel(
    const int* __restrict__ bucket_cnt, int* __restrict__ bucket_base,
    int* __restrict__ bucket_cur) {
  int t = threadIdx.x;
  int lane = t & 63, wid = t >> 6;
  int x = (t < NB) ? bucket_cnt[t] : 0;
  int incl = x;
#pragma unroll
  for (int d = 1; d < 64; d <<= 1) {
    int tt = __shfl_up(incl, d, 64);
    if (lane >= d) incl += tt;
  }
  __shared__ int ws[16];
  if (lane == 63) ws[wid] = incl;
  __syncthreads();
  int woff = 0;
  for (int k = 0; k < wid; ++k) woff += ws[k];
  int excl = woff + incl - x;
  if (t < NB) {
    bucket_base[t] = excl;
    bucket_cur[t] = excl;
  }
  if (t == NB - 1) bucket_base[NB] = excl + x;  // == 2*nnz
}

// ===========================================================================
// partition: per-block LDS hist -> chunk reserve -> write items to buckets
// item.x = (key_low8 << 18) | neighbor(17b), item.y = val bits
// ===========================================================================
__global__ __launch_bounds__(256) void partition_kernel(
    const int* __restrict__ rows, const int* __restrict__ cols,
    const float* __restrict__ vals, int* __restrict__ bucket_cur,
    int2* __restrict__ bkt_items, int nnz) {
  __shared__ int cnt[NB];
  __shared__ int wbase[NB];
  for (int k = threadIdx.x; k < NB; k += 256) cnt[k] = 0;
  __syncthreads();
  int start = blockIdx.x * PART_CHUNK;
  int end = start + PART_CHUNK;
  if (end > nnz) end = nnz;
  for (int i = start + threadIdx.x; i < end; i += 256) {
    int c = cols[i];
    int k = rows[i] + (c >= HALF_E ? NNODES : 0);
    atomicAdd(&cnt[c >> 8], 1);
    atomicAdd(&cnt[NB_E + (k >> 8)], 1);
  }
  __syncthreads();
  for (int k = threadIdx.x; k < NB; k += 256) {
    int c = cnt[k];
    wbase[k] = c ? atomicAdd(&bucket_cur[k], c) : 0;
    cnt[k] = 0;
  }
  __syncthreads();
  for (int i = start + threadIdx.x; i < end; i += 256) {
    int c = cols[i], r = rows[i];
    int v = __float_as_int(vals[i]);
    int be = c >> 8;
    int p = wbase[be] + atomicAdd(&cnt[be], 1);
    bkt_items[p] = make_int2(((c & 255) << 18) | r, v);
    int key = r + (c >= HALF_E ? NNODES : 0);
    int bn = NB_E + (key >> 8);
    int q = wbase[bn] + atomicAdd(&cnt[bn], 1);
    bkt_items[q] = make_int2(((key & 255) << 18) | c, v);
  }
}

// ===========================================================================
// place: one block per bucket; per-key LDS hist+scan; writes off[], pair[],
// edge scales (dein) and raw node-subkey degree sums (ddeg).
// ===========================================================================
__global__ __launch_bounds__(256) void place_kernel(
    const int* __restrict__ bucket_base, const int2* __restrict__ bkt_items,
    int* __restrict__ off, int2* __restrict__ pair, float* __restrict__ dein,
    float* __restrict__ ddeg) {
  int b = blockIdx.x;
  int s = bucket_base[b], e = bucket_base[b + 1];
  __shared__ int kcnt[256];
  __shared__ float ksum[256];
  __shared__ int kbase[256];
  __shared__ int ws[4];
  int t = threadIdx.x;
  kcnt[t] = 0;
  ksum[t] = 0.f;
  __syncthreads();
  for (int j = s + t; j < e; j += 256) {
    int2 it = bkt_items[j];
    int k = it.x >> 18;
    atomicAdd(&kcnt[k], 1);
    atomicAdd(&ksum[k], __int_as_float(it.y));
  }
  __syncthreads();
  int x = kcnt[t];
  int lane = t & 63, wid = t >> 6;
  int incl = x;
#pragma unroll
  for (int d = 1; d < 64; d <<= 1) {
    int tt = __shfl_up(incl, d, 64);
    if (lane >= d) incl += tt;
  }
  if (lane == 63) ws[wid] = incl;
  __syncthreads();
  int woff = 0;
  for (int k = 0; k < wid; ++k) woff += ws[k];
  int excl = woff + incl - x;
  kbase[t] = s + excl;
  if (b < NB_E) {
    int kglob = (b << 8) | t;
    if (kglob < NEDGES) {
      off[kglob] = s + excl;
      dein[kglob] = 1.0f / fmaxf(ksum[t], 1e-6f);
    }
  } else {
    int kglob = ((b - NB_E) << 8) | t;
    if (kglob < 2 * NNODES) {
      off[NEDGES + kglob] = s + excl;
      ddeg[kglob] = ksum[t];  // raw partial sum; combined in scalex
    }
  }
  if (b == NB - 1 && t == 255) off[NKEYS] = e;
  __syncthreads();
  kcnt[t] = 0;
  __syncthreads();
  for (int j = s + t; j < e; j += 256) {
    int2 it = bkt_items[j];
    int k = it.x >> 18;
    int pos = kbase[k] + atomicAdd(&kcnt[k], 1);
    pair[pos] = make_int2(it.x & 0x3FFFF, it.y);
  }
}

// ===========================================================================
// scalex: dvis[r] = rsqrt(clip(ddeg[r]+ddeg[N+r])); Pn (chunk-major) = dvis*X
// chunk-major: float4 (c, row, q4) at ((c*rows + row)*4 + q4)
// ===========================================================================
__global__ __launch_bounds__(256) void scalex_kernel(
    const float* __restrict__ X, const float* __restrict__ ddeg,
    float* __restrict__ dvis, float* __restrict__ Y) {
  int i = blockIdx.x * 256 + threadIdx.x;  // f4 index, row-major walk
  if (i >= NNODES * 32) return;
  int row = i >> 5, kk = i & 31;
  float s = rsqrtf(fmaxf(ddeg[row] + ddeg[NNODES + row], 1e-6f));
  if (kk == 0) dvis[row] = s;
  float4 v = reinterpret_cast<const float4*>(X)[i];
  size_t di = ((size_t)(kk >> 2) * NNODES + row) * 4 + (kk & 3);
  reinterpret_cast<float4*>(Y)[di] =
      make_float4(s * v.x, s * v.y, s * v.z, s * v.w);
}

// ===========================================================================
// gather8: XCD-sharded chunk-major gather. chunk = bid & 7 (pins to XCD via
// round-robin dispatch). Block: 64 groups x 4 lanes; group owns one segment's
// 64 B granule; lane l4 owns float4 l4. Src slice per XCD = nsrc*64B (3.2 MB
// for N=50K) -> L2-resident. accum: add into existing dst (node half-1).
// ===========================================================================
__global__ __launch_bounds__(256) void gather8_kernel(
    const float* __restrict__ src, float* __restrict__ dst,
    const int* __restrict__ off, const int2* __restrict__ pair,
    const float* __restrict__ seg_scale, int nseg, int nsrc, int accum) {
  int chunk = blockIdx.x & 7;
  int e = (blockIdx.x >> 3) * 64 + (threadIdx.x >> 2);
  if (e >= nseg) return;
  int l4 = threadIdx.x & 3;
  int s = off[e], t = off[e + 1];
  const float4* S4 =
      reinterpret_cast<const float4*>(src) + (size_t)chunk * nsrc * 4 + l4;
  float4 acc = make_float4(0.f, 0.f, 0.f, 0.f);
  int j = s;
  for (; j + 1 < t; j += 2) {
    int2 p0 = pair[j], p1 = pair[j + 1];
    float w0 = __int_as_float(p0.y), w1 = __int_as_float(p1.y);
    float4 x0 = S4[(size_t)p0.x * 4];
    float4 x1 = S4[(size_t)p1.x * 4];
    acc.x = fmaf(w0, x0.x, acc.x); acc.y = fmaf(w0, x0.y, acc.y);
    acc.z = fmaf(w0, x0.z, acc.z); acc.w = fmaf(w0, x0.w, acc.w);
    acc.x = fmaf(w1, x1.x, acc.x); acc.y = fmaf(w1, x1.y, acc.y);
    acc.z = fmaf(w1, x1.z, acc.z); acc.w = fmaf(w1, x1.w, acc.w);
  }
  if (j < t) {
    int2 p0 = pair[j];
    float w0 = __int_as_float(p0.y);
    float4 x0 = S4[(size_t)p0.x * 4];
    acc.x = fmaf(w0, x0.x, acc.x); acc.y = fmaf(w0, x0.y, acc.y);
    acc.z = fmaf(w0, x0.z, acc.z); acc.w = fmaf(w0, x0.w, acc.w);
  }
  if (seg_scale) {
    float sc = seg_scale[e];
    acc.x *= sc; acc.y *= sc; acc.z *= sc; acc.w *= sc;
  }
  size_t di = ((size_t)chunk * nseg + e) * 4 + l4;
  float4* D4 = reinterpret_cast<float4*>(dst);
  if (accum) {
    float4 p = D4[di];
    acc.x += p.x; acc.y += p.y; acc.z += p.z; acc.w += p.w;
  }
  D4[di] = acc;
}

// ===========================================================================
// GEMM (chunk-major X): out = act( dvis[n] * (Pn[n,:] @ W^T[:, j0:j0+64]) )
// Block 64 rows x 64 cols, blockIdx = rb*2 + jb. Swizzled LDS W^T half-tile.
// mode 0: s*acc -> row-major d_out | mode 1: s*relu(s*acc) -> chunk-major X1
// ===========================================================================
__global__ __launch_bounds__(256) void gemm_kernel(
    const float* __restrict__ Pn, const float* __restrict__ dvis,
    const float* __restrict__ W, float* __restrict__ out, int mode) {
  __shared__ float WT[128 * 64];  // 32 KB
  int t = threadIdx.x;
  int jb = blockIdx.x & 1;
  int rb = blockIdx.x >> 1;
  int j0 = jb << 6;

  {
    int K = t & 31;
    int Jb = t >> 5;
#pragma unroll
    for (int p = 0; p < 2; ++p) {
      int J = Jb + (p << 3);
      const float* Wb = W + (size_t)(j0 + 4 * J) * 128 + 4 * K;
      float4 g0 = *reinterpret_cast<const float4*>(Wb);
      float4 g1 = *reinterpret_cast<const float4*>(Wb + 128);
      float4 g2 = *reinterpret_cast<const float4*>(Wb + 256);
      float4 g3 = *reinterpret_cast<const float4*>(Wb + 384);
      const float* g0p = reinterpret_cast<const float*>(&g0);
      const float* g1p = reinterpret_cast<const float*>(&g1);
      const float* g2p = reinterpret_cast<const float*>(&g2);
      const float* g3p = reinterpret_cast<const float*>(&g3);
#pragma unroll
      for (int q = 0; q < 4; ++q) {
        int k = 4 * K + q;
        float4 hq = make_float4(g0p[q], g1p[q], g2p[q], g3p[q]);
        int slot = (J + k) & 15;
        *reinterpret_cast<float4*>(&WT[k * 64 + 4 * slot]) = hq;
      }
    }
  }
  __syncthreads();

  int u = t & 15;
  int rg = t >> 4;
  int rbase = rb * 64 + rg * 4;
  const float4* WT4 = reinterpret_cast<const float4*>(WT);
  float4 acc0 = make_float4(0.f, 0.f, 0.f, 0.f);
  float4 acc1 = acc0, acc2 = acc0, acc3 = acc0;

  int rr0 = rbase + 0; if (rr0 >= NNODES) rr0 = NNODES - 1;
  int rr1 = rbase + 1; if (rr1 >= NNODES) rr1 = NNODES - 1;
  int rr2 = rbase + 2; if (rr2 >= NNODES) rr2 = NNODES - 1;
  int rr3 = rbase + 3; if (rr3 >= NNODES) rr3 = NNODES - 1;
  const float4* Pn4 = reinterpret_cast<const float4*>(Pn);
  const float4* X0 = Pn4 + (size_t)rr0 * 4;
  const float4* X1 = Pn4 + (size_t)rr1 * 4;
  const float4* X2 = Pn4 + (size_t)rr2 * 4;
  const float4* X3 = Pn4 + (size_t)rr3 * 4;

#pragma unroll 4
  for (int kk = 0; kk < 32; ++kk) {
    size_t xi = (size_t)(kk >> 2) * (NNODES * 4) + (kk & 3);
    float4 x0 = X0[xi], x1 = X1[xi], x2 = X2[xi], x3 = X3[xi];
    const float* x0p = reinterpret_cast<const float*>(&x0);
    const float* x1p = reinterpret_cast<const float*>(&x1);
    const float* x2p = reinterpret_cast<const float*>(&x2);
    const float* x3p = reinterpret_cast<const float*>(&x3);
#pragma unroll
    for (int q = 0; q < 4; ++q) {
      int k = 4 * kk + q;
      float4 w4 = WT4[k * 16 + ((u + k) & 15)];
      acc0.x = fmaf(x0p[q], w4.x, acc0.x); acc0.y = fmaf(x0p[q], w4.y, acc0.y);
      acc0.z = fmaf(x0p[q], w4.z, acc0.z); acc0.w = fmaf(x0p[q], w4.w, acc0.w);
      acc1.x = fmaf(x1p[q], w4.x, acc1.x); acc1.y = fmaf(x1p[q], w4.y, acc1.y);
      acc1.z = fmaf(x1p[q], w4.z, acc1.z); acc1.w = fmaf(x1p[q], w4.w, acc1.w);
      acc2.x = fmaf(x2p[q], w4.x, acc2.x); acc2.y = fmaf(x2p[q], w4.y, acc2.y);
      acc2.z = fmaf(x2p[q], w4.z, acc2.z); acc2.w = fmaf(x2p[q], w4.w, acc2.w);
      acc3.x = fmaf(x3p[q], w4.x, acc3.x); acc3.y = fmaf(x3p[q], w4.y, acc3.y);
      acc3.z = fmaf(x3p[q], w4.z, acc3.z); acc3.w = fmaf(x3p[q], w4.w, acc3.w);
    }
  }

#pragma unroll
  for (int m = 0; m < 4; ++m) {
    int r = rbase + m;
    if (r >= NNODES) break;
    float4 a = (m == 0) ? acc0 : (m == 1) ? acc1 : (m == 2) ? acc2 : acc3;
    float s = dvis[r];
    float4 o = make_float4(s * a.x, s * a.y, s * a.z, s * a.w);
    if (mode == 1) {
      o.x = fmaxf(o.x, 0.f) * s; o.y = fmaxf(o.y, 0.f) * s;
      o.z = fmaxf(o.z, 0.f) * s; o.w = fmaxf(o.w, 0.f) * s;
      int c_out = (j0 >> 4) + (u >> 2);
      reinterpret_cast<float4*>(out)[((size_t)c_out * NNODES + r) * 4 +
                                     (u & 3)] = o;
    } else {
      *reinterpret_cast<float4*>(&out[(size_t)r * 128 + j0 + 4 * u]) = o;
    }
  }
}

// ===========================================================================
// Fallback (atomic-scatter, row-major) kernels — used only if ws too small
// ===========================================================================
__global__ __launch_bounds__(256) void deg_fb_kernel(
    const int* __restrict__ rows, const int* __restrict__ cols,
    const float* __restrict__ vals, float* __restrict__ dv,
    float* __restrict__ de, int nnz) {
  int i = blockIdx.x * 256 + threadIdx.x;
  if (i >= nnz) return;
  float v = vals[i];
  unsafeAtomicAdd(&dv[rows[i]], v);
  unsafeAtomicAdd(&de[cols[i]], v);
}

__global__ __launch_bounds__(256) void inv_kernel(float* __restrict__ dv,
                                                  float* __restrict__ de) {
  int i = blockIdx.x * 256 + threadIdx.x;
  if (i < NNODES) {
    dv[i] = 1.0f / sqrtf(fmaxf(dv[i], 1e-6f));
  } else if (i < NNODES + NEDGES) {
    int j = i - NNODES;
    de[j] = 1.0f / fmaxf(de[j], 1e-6f);
  }
}

__global__ __launch_bounds__(256) void scatter_edge_kernel(
    const float* __restrict__ X, float* __restrict__ Ye,
    const int* __restrict__ rows, const int* __restrict__ cols,
    const float* __restrict__ vals, const float* __restrict__ dvis, int nnz) {
  int g = (blockIdx.x * 256 + threadIdx.x) >> 5;
  int lane = threadIdx.x & 31;
  if (g >= nnz) return;
  int r = rows[g], c = cols[g];
  float s = vals[g] * dvis[r];
  float4 x = reinterpret_cast<const float4*>(X)[(size_t)r * 32 + lane];
  float* dst = Ye + (size_t)c * HID + lane * 4;
  unsafeAtomicAdd(dst + 0, s * x.x);
  unsafeAtomicAdd(dst + 1, s * x.y);
  unsafeAtomicAdd(dst + 2, s * x.z);
  unsafeAtomicAdd(dst + 3, s * x.w);
}

__global__ __launch_bounds__(256) void scatter_node_kernel(
    const float* __restrict__ Ye, float* __restrict__ Yn,
    const int* __restrict__ rows, const int* __restrict__ cols,
    const float* __restrict__ vals, const float* __restrict__ dein, int nnz) {
  int g = (blockIdx.x * 256 + threadIdx.x) >> 5;
  int lane = threadIdx.x & 31;
  if (g >= nnz) return;
  int r = rows[g], c = cols[g];
  float s = vals[g] * dein[c];
  float4 y = reinterpret_cast<const float4*>(Ye)[(size_t)c * 32 + lane];
  float* dst = Yn + (size_t)r * HID + lane * 4;
  unsafeAtomicAdd(dst + 0, s * y.x);
  unsafeAtomicAdd(dst + 1, s * y.y);
  unsafeAtomicAdd(dst + 2, s * y.z);
  unsafeAtomicAdd(dst + 3, s * y.w);
}

// row-major GEMM for fallback path. mode 2: relu(s*acc), mode 0: s*acc
__global__ __launch_bounds__(256) void gemm_rm_kernel(
    const float* __restrict__ Pn, const float* __restrict__ dvis,
    const float* __restrict__ W, float* __restrict__ out, int mode) {
  __shared__ float WT[128 * 64];
  int t = threadIdx.x;
  int jb = blockIdx.x & 1;
  int rb = blockIdx.x >> 1;
  int j0 = jb << 6;
  {
    int K = t & 31;
    int Jb = t >> 5;
#pragma unroll
    for (int p = 0; p < 2; ++p) {
      int J = Jb + (p << 3);
      const float* Wb = W + (size_t)(j0 + 4 * J) * 128 + 4 * K;
      float4 g0 = *reinterpret_cast<const float4*>(Wb);
      float4 g1 = *reinterpret_cast<const float4*>(Wb + 128);
      float4 g2 = *reinterpret_cast<const float4*>(Wb + 256);
      float4 g3 = *reinterpret_cast<const float4*>(Wb + 384);
      const float* g0p = reinterpret_cast<const float*>(&g0);
      const float* g1p = reinterpret_cast<const float*>(&g1);
      const float* g2p = reinterpret_cast<const float*>(&g2);
      const float* g3p = reinterpret_cast<const float*>(&g3);
#pragma unroll
      for (int q = 0; q < 4; ++q) {
        int k = 4 * K + q;
        float4 hq = make_float4(g0p[q], g1p[q], g2p[q], g3p[q]);
        int slot = (J + k) & 15;
        *reinterpret_cast<float4*>(&WT[k * 64 + 4 * slot]) = hq;
      }
    }
  }
  __syncthreads();
  int u = t & 15;
  int rg = t >> 4;
  int rbase = rb * 64 + rg * 4;
  const float4* WT4 = reinterpret_cast<const float4*>(WT);
  float4 acc0 = make_float4(0.f, 0.f, 0.f, 0.f);
  float4 acc1 = acc0, acc2 = acc0, acc3 = acc0;
  int rr0 = rbase + 0; if (rr0 >= NNODES) rr0 = NNODES - 1;
  int rr1 = rbase + 1; if (rr1 >= NNODES) rr1 = NNODES - 1;
  int rr2 = rbase + 2; if (rr2 >= NNODES) rr2 = NNODES - 1;
  int rr3 = rbase + 3; if (rr3 >= NNODES) rr3 = NNODES - 1;
  const float4* X0 = reinterpret_cast<const float4*>(Pn + (size_t)rr0 * 128);
  const float4* X1 = reinterpret_cast<const float4*>(Pn + (size_t)rr1 * 128);
  const float4* X2 = reinterpret_cast<const float4*>(Pn + (size_t)rr2 * 128);
  const float4* X3 = reinterpret_cast<const float4*>(Pn + (size_t)rr3 * 128);
#pragma unroll 4
  for (int kk = 0; kk < 32; ++kk) {
    float4 x0 = X0[kk], x1 = X1[kk], x2 = X2[kk], x3 = X3[kk];
    const float* x0p = reinterpret_cast<const float*>(&x0);
    const float* x1p = reinterpret_cast<const float*>(&x1);
    const float* x2p = reinterpret_cast<const float*>(&x2);
    const float* x3p = reinterpret_cast<const float*>(&x3);
#pragma unroll
    for (int q = 0; q < 4; ++q) {
      int k = 4 * kk + q;
      float4 w4 = WT4[k * 16 + ((u + k) & 15)];
      acc0.x = fmaf(x0p[q], w4.x, acc0.x); acc0.y = fmaf(x0p[q], w4.y, acc0.y);
      acc0.z = fmaf(x0p[q], w4.z, acc0.z); acc0.w = fmaf(x0p[q], w4.w, acc0.w);
      acc1.x = fmaf(x1p[q], w4.x, acc1.x); acc1.y = fmaf(x1p[q], w4.y, acc1.y);
      acc1.z = fmaf(x1p[q], w4.z, acc1.z); acc1.w = fmaf(x1p[q], w4.w, acc1.w);
      acc2.x = fmaf(x2p[q], w4.x, acc2.x); acc2.y = fmaf(x2p[q], w4.y, acc2.y);
      acc2.z = fmaf(x2p[q], w4.z, acc2.z); acc2.w = fmaf(x2p[q], w4.w, acc2.w);
      acc3.x = fmaf(x3p[q], w4.x, acc3.x); acc3.y = fmaf(x3p[q], w4.y, acc3.y);
      acc3.z = fmaf(x3p[q], w4.z, acc3.z); acc3.w = fmaf(x3p[q], w4.w, acc3.w);
    }
  }
#pragma unroll
  for (int m = 0; m < 4; ++m) {
    int r = rbase + m;
    if (r >= NNODES) break;
    float4 a = (m == 0) ? acc0 : (m == 1) ? acc1 : (m == 2) ? acc2 : acc3;
    float s = dvis[r];
    float4 o = make_float4(s * a.x, s * a.y, s * a.z, s * a.w);
    if (mode == 2) {
      o.x = fmaxf(o.x, 0.f); o.y = fmaxf(o.y, 0.f);
      o.z = fmaxf(o.z, 0.f); o.w = fmaxf(o.w, 0.f);
    }
    *reinterpret_cast<float4*>(&out[(size_t)r * 128 + j0 + 4 * u]) = o;
  }
}

// ===========================================================================
extern "C" void kernel_launch(void* const* d_in, const int* in_sizes, int n_in,
                              void* d_out, int out_size, void* d_ws,
                              size_t ws_size, hipStream_t stream) {
  const int* rows = (const int*)d_in[0];
  const int* cols = (const int*)d_in[1];
  const float* vals = (const float*)d_in[2];
  const float* X0 = (const float*)d_in[3];
  const float* W0 = (const float*)d_in[4];
  const float* W1 = (const float*)d_in[5];
  const int nnz = in_sizes[0];
  float* out = (float*)d_out;

  const int gemm_blocks = ((NNODES + 63) / 64) * 2;

  // CSR-path workspace layout:
  // pair[2*nnz int2] | Ye[E*HID] (aliases bkt_items) | Pn[N*HID] | dvis[N] |
  // dein[E] | ddeg[2N] | off[NKEYS+1] | bucket_cnt[NB] | bucket_base[NB+1] |
  // bucket_cur[NB]
  size_t elems = 4 * (size_t)nnz + (size_t)NEDGES * HID +
                 (size_t)NNODES * HID + NNODES + NEDGES + 2 * NNODES +
                 (NKEYS + 1) + NB + (NB + 1) + NB;
  size_t need = elems * 4;
  bool bkt_fits = (size_t)4 * nnz <= (size_t)NEDGES * HID;

  if (ws_size >= need && bkt_fits) {
    int2* pair = (int2*)d_ws;
    float* Ye = (float*)(pair + 2 * (size_t)nnz);
    int2* bkt_items = (int2*)Ye;  // preprocessing alias
    float* Pn = Ye + (size_t)NEDGES * HID;
    float* dvis = Pn + (size_t)NNODES * HID;
    float* dein = dvis + NNODES;
    float* ddeg = dein + NEDGES;
    int* off = (int*)(ddeg + 2 * NNODES);
    int* bucket_cnt = off + NKEYS + 1;
    int* bucket_base = bucket_cnt + NB;
    int* bucket_cur = bucket_base + NB + 1;

    hipMemsetAsync(bucket_cnt, 0, NB * sizeof(int), stream);
    bucket_count_kernel<<<240, 256, 0, stream>>>(rows, cols, bucket_cnt, nnz);
    bucket_scan_kernel<<<1, 1024, 0, stream>>>(bucket_cnt, bucket_base,
                                               bucket_cur);
    partition_kernel<<<(nnz + PART_CHUNK - 1) / PART_CHUNK, 256, 0, stream>>>(
        rows, cols, vals, bucket_cur, bkt_items, nnz);
    place_kernel<<<NB, 256, 0, stream>>>(bucket_base, bkt_items, off, pair,
                                         dein, ddeg);
    scalex_kernel<<<(NNODES * 32 + 255) / 256, 256, 0, stream>>>(X0, ddeg,
                                                                 dvis, Pn);

    const int eg_blocks = ((NEDGES + 63) / 64) * 8;
    const int ng_blocks = ((NNODES + 63) / 64) * 8;

    // layer 1
    gather8_kernel<<<eg_blocks, 256, 0, stream>>>(Pn, Ye, off, pair, dein,
                                                  NEDGES, NNODES, 0);
    gather8_kernel<<<ng_blocks, 256, 0, stream>>>(Ye, Pn, off + NEDGES, pair,
                                                  nullptr, NNODES, NEDGES, 0);
    gather8_kernel<<<ng_blocks, 256, 0, stream>>>(
        Ye, Pn, off + NEDGES + NNODES, pair, nullptr, NNODES, NEDGES, 1);
    gemm_kernel<<<gemm_blocks, 256, 0, stream>>>(Pn, dvis, W0, out, 1);

    // layer 2 (X1 chunk-major in d_out)
    gather8_kernel<<<eg_blocks, 256, 0, stream>>>(out, Ye, off, pair, dein,
                                                  NEDGES, NNODES, 0);
    gather8_kernel<<<ng_blocks, 256, 0, stream>>>(Ye, Pn, off + NEDGES, pair,
                                                  nullptr, NNODES, NEDGES, 0);
    gather8_kernel<<<ng_blocks, 256, 0, stream>>>(
        Ye, Pn, off + NEDGES + NNODES, pair, nullptr, NNODES, NEDGES, 1);
    gemm_kernel<<<gemm_blocks, 256, 0, stream>>>(Pn, dvis, W1, out, 0);
    return;
  }

  // ---------- fallback: atomic-scatter path (row-major) ----------
  float* dv = (float*)d_ws;
  float* de = dv + NNODES;
  float* Ye = de + NEDGES;
  float* Pn = Ye + (size_t)NEDGES * HID;
  const int scat_blocks = (nnz + 7) / 8;

  hipMemsetAsync(dv, 0, (size_t)(NNODES + NEDGES) * sizeof(float), stream);
  deg_fb_kernel<<<(nnz + 255) / 256, 256, 0, stream>>>(rows, cols, vals, dv,
                                                       de, nnz);
  inv_kernel<<<(NNODES + NEDGES + 255) / 256, 256, 0, stream>>>(dv, de);

  hipMemsetAsync(Ye, 0, (size_t)NEDGES * HID * sizeof(float), stream);
  scatter_edge_kernel<<<scat_blocks, 256, 0, stream>>>(X0, Ye, rows, cols,
                                                       vals, dv, nnz);
  hipMemsetAsync(Pn, 0, (size_t)NNODES * HID * sizeof(float), stream);
  scatter_node_kernel<<<scat_blocks, 256, 0, stream>>>(Ye, Pn, rows, cols,
                                                       vals, de, nnz);
  gemm_rm_kernel<<<gemm_blocks, 256, 0, stream>>>(Pn, dv, W0, out, 2);

  hipMemsetAsync(Ye, 0, (size_t)NEDGES * HID * sizeof(float), stream);
  scatter_edge_kernel<<<scat_blocks, 256, 0, stream>>>(out, Ye, rows, cols,
                                                       vals, dv, nnz);
  hipMemsetAsync(Pn, 0, (size_t)NNODES * HID * sizeof(float), stream);
  scatter_node_kernel<<<scat_blocks, 256, 0, stream>>>(Ye, Pn, rows, cols,
                                                       vals, de, nnz);
  gemm_rm_kernel<<<gemm_blocks, 256, 0, stream>>>(Pn, dv, W1, out, 0);
}